// Round 16
// baseline (151.397 us; speedup 1.0000x reference)
//
#include <hip/hip_runtime.h>
#include <hip/hip_bf16.h>
#include <stdint.h>

typedef __bf16 bf16;
typedef __bf16 bf16x8 __attribute__((ext_vector_type(8)));
typedef __bf16 bf16x4 __attribute__((ext_vector_type(4)));
typedef float  f32x4  __attribute__((ext_vector_type(4)));
typedef int    i32x4  __attribute__((ext_vector_type(4)));

#define MFMA16(a, b, c) __builtin_amdgcn_mfma_f32_16x16x32_bf16((a), (b), (c), 0, 0, 0)

#define GLOAD16(gp, lp) __builtin_amdgcn_global_load_lds(                     \
    (__attribute__((address_space(1))) void*)(gp),                            \
    (__attribute__((address_space(3))) void*)(lp), 16, 0, 0)

// Attn K/V LDS tiles are [rows][64] bf16; GEMM tiles [rows][32] bf16, both
// with granule XOR swizzle (staging pre-swizzles the GLOBAL source column;
// LDS dest stays linear for global_load_lds).
//
// V's key axis is sigma-permuted in global memory:
//   key s = 16n+4g+r  ->  sigma(s) = 32*(n&1) + 8*g + 4*(n>>1) + r
// so P stays register-resident in attn (see k_attn header).
//
// QKV GEMM (r16): per-wave output 128x64 (acc[8][4]) in a 128x256 4-wave
// WG tile. r13-r15 proved QKV is LDS-BANDWIDTH-bound (3 wait schemes
// identical; 144 KB/step/CU at ~128 B/cyc == measured 48 us). Bigger
// per-wave tiles cut LDS bytes/FLOP 1.5x (12 KB reads / 32 MFMA vs
// 8 KB / 16) and halve staging per FLOP. 72 KB LDS, 2 WG/CU, ~200 VGPR
// (2 waves/SIMD). Out-GEMM keeps the 128x128 loop (latency-bound, not
// LDS-bound, at 1 WG/CU).

// ---------------------------------------------------------------- prep ----
__global__ __launch_bounds__(256) void k_prep(
    const float* __restrict__ x,
    const float* __restrict__ Wq, const float* __restrict__ Wk,
    const float* __restrict__ Wv, const float* __restrict__ Wo,
    bf16* __restrict__ xb, bf16* __restrict__ wqkvt, bf16* __restrict__ wot,
    float* __restrict__ ct, float* __restrict__ st) {
    __shared__ float t[32][33];
    const int bid = blockIdx.x, tid = threadIdx.x;
    if (bid < 4096) {
        const int i = bid * 256 + tid;
        float4 v = ((const float4*)x)[i];
        bf16x4 o;
        o[0] = (bf16)v.x; o[1] = (bf16)v.y; o[2] = (bf16)v.z; o[3] = (bf16)v.w;
        ((bf16x4*)xb)[i] = o;
    } else if (bid < 4352) {
        const int i = (bid - 4096) * 256 + tid;  // 65536
        const int s = i >> 5, j = i & 31;
        const float inv = expf(-(float)j * (9.210340371976184f / 32.0f)); // 10000^(-j/32)
        const float a = (float)s * inv;
        ct[i] = cosf(a);
        st[i] = sinf(a);
    } else {
        const int wb = bid - 4352;
        const int z = wb >> 10, tb = wb & 1023;
        const float* src = (z == 0) ? Wq : (z == 1) ? Wk : (z == 2) ? Wv : Wo;
        bf16* dst = (z < 3) ? wqkvt + (size_t)z * 1024 * 1024 : wot;
        const int bx = (tb & 31) * 32, by = (tb >> 5) * 32;
        const int tx = tid & 31, ty = tid >> 5;
#pragma unroll
        for (int i = 0; i < 32; i += 8)
            t[ty + i][tx] = src[(size_t)(by + ty + i) * 1024 + bx + tx];
        __syncthreads();
#pragma unroll
        for (int i = 0; i < 32; i += 8)
            dst[(size_t)(bx + ty + i) * 1024 + by + tx] = (bf16)t[tx][ty + i];
    }
}

// ------------------------------------------- out-GEMM mainloop (128x128) ----
__device__ __forceinline__ void gemm_loop(const bf16* __restrict__ A,
                                          const bf16* __restrict__ Bt,
                                          int m0, int n0,
                                          bf16* As, bf16* Bs,
                                          f32x4 (&acc)[4][4]) {
    const int tid  = threadIdx.x;
    const int w    = tid >> 6, lane = tid & 63;
    const int wr   = (w >> 1) * 64, wc = (w & 1) * 64;
    const int l15  = lane & 15, l4 = lane >> 4;
    const int srow = w * 16 + (lane >> 2);
    const int skol = 8 * ((lane & 3) ^ ((lane >> 3) & 3));
    const int rdb  = l15 * 32 + 8 * (l4 ^ ((l15 >> 1) & 3));
    const bf16* Ap = A  + (size_t)(m0 + srow) * 1024 + skol;
    const bf16* Bp = Bt + (size_t)(n0 + srow) * 1024 + skol;

#define GSTAGE(B, kt) do {                                                   \
        GLOAD16(Ap + (kt),         As + (B) * 4096 + w * 512);               \
        GLOAD16(Ap + 65536 + (kt), As + (B) * 4096 + 2048 + w * 512);        \
        GLOAD16(Bp + (kt),         Bs + (B) * 4096 + w * 512);               \
        GLOAD16(Bp + 65536 + (kt), Bs + (B) * 4096 + 2048 + w * 512);        \
    } while (0)

#define GCOMP(B) do {                                                        \
        bf16x8 af[4], bfv[4];                                                \
        _Pragma("unroll")                                                    \
        for (int m = 0; m < 4; ++m)                                          \
            af[m] = *(const bf16x8*)(As + (B) * 4096 + (wr + 16 * m) * 32 + rdb); \
        _Pragma("unroll")                                                    \
        for (int n = 0; n < 4; ++n)                                          \
            bfv[n] = *(const bf16x8*)(Bs + (B) * 4096 + (wc + 16 * n) * 32 + rdb); \
        __builtin_amdgcn_s_setprio(1);                                       \
        _Pragma("unroll")                                                    \
        for (int m = 0; m < 4; ++m)                                          \
            _Pragma("unroll")                                                \
            for (int n = 0; n < 4; ++n)                                      \
                acc[m][n] = MFMA16(af[m], bfv[n], acc[m][n]);                \
        __builtin_amdgcn_s_setprio(0);                                       \
    } while (0)

    GSTAGE(0, 0);
    GSTAGE(1, 32);
    for (int i = 0; i < 30; i += 3) {
        asm volatile("s_waitcnt vmcnt(8)" ::: "memory");
        __builtin_amdgcn_s_barrier();
        GSTAGE(2, (i + 2) * 32);
        GCOMP(0);
        asm volatile("s_waitcnt vmcnt(8)" ::: "memory");
        __builtin_amdgcn_s_barrier();
        GSTAGE(0, (i + 3) * 32);
        GCOMP(1);
        asm volatile("s_waitcnt vmcnt(8)" ::: "memory");
        __builtin_amdgcn_s_barrier();
        GSTAGE(1, (i + 4) * 32);
        GCOMP(2);
    }
    asm volatile("s_waitcnt vmcnt(8)" ::: "memory");
    __builtin_amdgcn_s_barrier();
    GCOMP(0);
    asm volatile("s_waitcnt vmcnt(0)" ::: "memory");
    __builtin_amdgcn_s_barrier();
    GCOMP(1);
#undef GCOMP
#undef GSTAGE
}

// ------------------------------------------------------------ GEMM QKV ----
// 128(M)x256(N) WG tile, 4 waves 1Mx4N (wave output 128x64, acc[8][4]),
// BK=32, 3-buffer LDS (A 24 KB + B 48 KB), prefetch distance 2, vmcnt(6)
// (6 gloads per stage per thread). Grid 12x32 = 384 WGs, 2 WG/CU.
__global__ __launch_bounds__(256) void k_gemm_qkv(
    const bf16* __restrict__ X, const bf16* __restrict__ Wt,
    const float* __restrict__ bq, const float* __restrict__ bk,
    const float* __restrict__ bv,
    const float* __restrict__ ct, const float* __restrict__ st,
    bf16* __restrict__ qbuf, bf16* __restrict__ kbuf, bf16* __restrict__ vtb) {
    __shared__ __align__(16) bf16 As[3 * 4096];   // [buf][128r][32]
    __shared__ __align__(16) bf16 Bs[3 * 8192];   // [buf][256r][32]
    f32x4 acc[8][4] = {};

    const int nwg = gridDim.x * gridDim.y;        // 384, %8 == 0
    const int wg  = blockIdx.y * gridDim.x + blockIdx.x;
    const int sw  = (wg & 7) * (nwg >> 3) + (wg >> 3);
    const int n0 = (sw % gridDim.x) * 256, m0 = (sw / gridDim.x) * 128;

    const int tid  = threadIdx.x;
    const int w    = tid >> 6, lane = tid & 63;
    const int l15  = lane & 15, l4 = lane >> 4;
    const int srow = w * 16 + (lane >> 2);
    const int skol = 8 * ((lane & 3) ^ ((lane >> 3) & 3));
    const int rdb  = l15 * 32 + 8 * (l4 ^ ((l15 >> 1) & 3));
    const bf16* Ap = X  + (size_t)(m0 + srow) * 1024 + skol;
    const bf16* Bp = Wt + (size_t)(n0 + srow) * 1024 + skol;

#define WSTAGE(B, kt) do {                                                   \
        GLOAD16(Ap + (kt),          As + (B) * 4096 + w * 512);              \
        GLOAD16(Ap + 65536 + (kt),  As + (B) * 4096 + 2048 + w * 512);       \
        GLOAD16(Bp + (kt),          Bs + (B) * 8192 + w * 512);              \
        GLOAD16(Bp + 65536 + (kt),  Bs + (B) * 8192 + 2048 + w * 512);       \
        GLOAD16(Bp + 131072 + (kt), Bs + (B) * 8192 + 4096 + w * 512);       \
        GLOAD16(Bp + 196608 + (kt), Bs + (B) * 8192 + 6144 + w * 512);       \
    } while (0)

#define WCOMP(B) do {                                                        \
        bf16x8 bfv[4], af[8];                                                \
        _Pragma("unroll")                                                    \
        for (int n = 0; n < 4; ++n)                                          \
            bfv[n] = *(const bf16x8*)(Bs + (B) * 8192 + w * 2048 + n * 512 + rdb); \
        _Pragma("unroll")                                                    \
        for (int m = 0; m < 8; ++m)                                          \
            af[m] = *(const bf16x8*)(As + (B) * 4096 + m * 512 + rdb);       \
        __builtin_amdgcn_s_setprio(1);                                       \
        _Pragma("unroll")                                                    \
        for (int m = 0; m < 8; ++m)                                          \
            _Pragma("unroll")                                                \
            for (int n = 0; n < 4; ++n)                                      \
                acc[m][n] = MFMA16(af[m], bfv[n], acc[m][n]);                \
        __builtin_amdgcn_s_setprio(0);                                       \
    } while (0)

    WSTAGE(0, 0);
    WSTAGE(1, 32);
    for (int i = 0; i < 30; i += 3) {
        asm volatile("s_waitcnt vmcnt(6)" ::: "memory");
        __builtin_amdgcn_s_barrier();
        WSTAGE(2, (i + 2) * 32);
        WCOMP(0);
        asm volatile("s_waitcnt vmcnt(6)" ::: "memory");
        __builtin_amdgcn_s_barrier();
        WSTAGE(0, (i + 3) * 32);
        WCOMP(1);
        asm volatile("s_waitcnt vmcnt(6)" ::: "memory");
        __builtin_amdgcn_s_barrier();
        WSTAGE(1, (i + 4) * 32);
        WCOMP(2);
    }
    asm volatile("s_waitcnt vmcnt(6)" ::: "memory");
    __builtin_amdgcn_s_barrier();
    WCOMP(0);
    asm volatile("s_waitcnt vmcnt(0)" ::: "memory");
    __builtin_amdgcn_s_barrier();
    WCOMP(1);
#undef WCOMP
#undef WSTAGE

    // epilogue
    const int featbase = n0 + w * 64;      // 64-aligned -> one head, one kind
    const int kind = featbase >> 10;       // 0=Q 1=K 2=V
    const int col0 = featbase & 1023;
    const int h = col0 >> 6;
    const float* bias = (kind == 0) ? bq : (kind == 1) ? bk : bv;
    // Q folds 1/sqrt(64) AND log2(e): attn then uses p = exp2(s) directly.
    const float oscale = (kind == 0) ? 0.18033688011112042f : 1.0f;

#pragma unroll
    for (int m = 0; m < 8; ++m) {
#pragma unroll
        for (int j = 0; j < 4; ++j) {
            const int tok = m0 + 16 * m + 4 * l4 + j;
            const int b = tok >> 11, s = tok & 2047;
            float vals[4];
#pragma unroll
            for (int n = 0; n < 4; ++n)
                vals[n] = acc[m][n][j] + bias[col0 + 16 * n + l15];
            if (kind < 2) {
                bf16* dst = (kind == 0) ? qbuf : kbuf;
                const size_t base = ((size_t)((b * 16 + h) * 2048 + s)) * 64;
#pragma unroll
                for (int n = 0; n < 4; ++n) {
                    const int dd = 16 * n + l15;          // 0..63
                    const int jr = dd & 31;
                    const float c = ct[s * 32 + jr], sn = st[s * 32 + jr];
                    const float other = vals[n ^ 2];       // d +/- 32 partner
                    const float rot = (dd < 32) ? -other : other;
                    dst[base + dd] = (bf16)((vals[n] * c + rot * sn) * oscale);
                }
            } else {
                // sigma-permute key position: s=16n+4g+r -> 32*(n&1)+8*g+4*(n>>1)+r
                const int sp = (s & ~63) | ((s & 0x1C) << 1) | ((s & 0x20) >> 3) | (s & 3);
#pragma unroll
                for (int n = 0; n < 4; ++n) {
                    const int dd = 16 * n + l15;
                    vtb[((size_t)((b * 16 + h) * 64 + dd)) * 2048 + sp] = (bf16)vals[n];
                }
            }
        }
    }
}

// ---------------------------------------------------------- attention ----
// 8 waves/WG, split-K: team = w>>2 handles keys [team*1024, +1024); wt = w&3.
// Each team: KBLK=64, 2-buffer static-indexed K/V, one vmcnt(0)+barrier per
// tile. Softmax pack: raw v_exp_f32 + v_cvt_pk_bf16_f32.
__global__ __launch_bounds__(512) void k_attn(const bf16* __restrict__ qbuf,
                                              const bf16* __restrict__ kbuf,
                                              const bf16* __restrict__ vtb,
                                              bf16* __restrict__ ob) {
    // [team][K/V][buf][4096] bf16 = 64 KB; team1 region doubles as merge buf
    __shared__ __align__(16) bf16 smem[2 * 2 * 2 * 4096];

    const int tid = threadIdx.x, w = tid >> 6, lane = tid & 63;
    const int team = w >> 2, wt = w & 3;
    const int l15 = lane & 15, l4 = lane >> 4;

    // XCD swizzle: 512 blocks round-robin over 8 XCDs; each XCD owns 4 heads.
    const int sid = blockIdx.x;
    const int bh  = (sid & 7) * 4 + ((sid >> 3) >> 4);
    const int qb0 = ((sid >> 3) & 15) * 128;
    const int b = bh >> 4, h = bh & 15;

    // Q fragments (2 per wave, same rows for both teams); force-complete.
    const bf16* qp = qbuf + ((size_t)bh * 2048 + qb0 + wt * 32 + l15) * 64 + 8 * l4;
    i32x4 qr00 = *(const i32x4*)qp;
    i32x4 qr01 = *(const i32x4*)(qp + 32);
    i32x4 qr10 = *(const i32x4*)(qp + 16 * 64);
    i32x4 qr11 = *(const i32x4*)(qp + 16 * 64 + 32);
    asm volatile("" :: "v"(qr00), "v"(qr01), "v"(qr10), "v"(qr11));
    asm volatile("s_waitcnt vmcnt(0)" ::: "memory");
    bf16x8 aq[2][2];
    aq[0][0] = __builtin_bit_cast(bf16x8, qr00);
    aq[0][1] = __builtin_bit_cast(bf16x8, qr01);
    aq[1][0] = __builtin_bit_cast(bf16x8, qr10);
    aq[1][1] = __builtin_bit_cast(bf16x8, qr11);

    bf16x8 ones;
#pragma unroll
    for (int i = 0; i < 8; ++i) ones[i] = (bf16)1.0f;

    f32x4 ao[2][4] = {};
    f32x4 lacc[2] = {};
    const f32x4 zf = {0.f, 0.f, 0.f, 0.f};

    const int r8   = lane >> 3;
    const int skol = 8 * ((lane & 7) ^ r8);           // pre-swizzled source col
    const int rdb  = l15 * 64 + 32 * ((l15 >> 2) & 1) + 8 * (l4 ^ (l15 & 3));
    // global K/V base for this team's key half
    const bf16* kp = kbuf + (size_t)bh * 131072 + (size_t)team * 65536
                   + (size_t)(wt * 8 + r8) * 64 + skol;
    const bf16* vp = vtb  + (size_t)bh * 131072 + (size_t)(wt * 8 + r8) * 2048
                   + team * 1024 + skol;
    // per-team LDS bases
    bf16* sK = smem + team * 16384;            // + B*4096
    bf16* sV = smem + team * 16384 + 8192;     // + B*4096
    const bf16* pK0 = sK + rdb;
    const bf16* pK1 = sK + (rdb ^ 32);
    const bf16* pV0 = sV + rdb;
    const bf16* pV1 = sV + (rdb ^ 32);

#define STAGE(B, t) do {                                                  \
        GLOAD16(kp + (size_t)(t) * 4096,        sK + (B) * 4096 + wt * 512);        \
        GLOAD16(kp + (size_t)(t) * 4096 + 2048, sK + (B) * 4096 + 2048 + wt * 512); \
        GLOAD16(vp + (t) * 64,                  sV + (B) * 4096 + wt * 512);        \
        GLOAD16(vp + 65536 + (t) * 64,          sV + (B) * 4096 + 2048 + wt * 512); \
    } while (0)

#define TILE(t, B) do {                                                       \
        asm volatile("s_waitcnt vmcnt(0)" ::: "memory");                      \
        __builtin_amdgcn_s_barrier();                                         \
        if ((t) < 15) STAGE((B) ^ 1, (t) + 1);                                \
        bf16x8 kfr[2][4], vfr[2][4];                                          \
        _Pragma("unroll")                                                     \
        for (int n = 0; n < 4; ++n) {                                         \
            kfr[0][n] = *(const bf16x8*)(pK0 + (B) * 4096 + n * 1024);        \
            kfr[1][n] = *(const bf16x8*)(pK1 + (B) * 4096 + n * 1024);        \
            vfr[0][n] = *(const bf16x8*)(pV0 + (B) * 4096 + n * 1024);        \
            vfr[1][n] = *(const bf16x8*)(pV1 + (B) * 4096 + n * 1024);        \
        }                                                                     \
        f32x4 sc[2][4];                                                       \
        __builtin_amdgcn_s_setprio(1);                                        \
        _Pragma("unroll")                                                     \
        for (int n = 0; n < 4; ++n) {                                         \
            sc[0][n] = MFMA16(kfr[0][n], aq[0][0], zf);                       \
            sc[1][n] = MFMA16(kfr[0][n], aq[1][0], zf);                       \
        }                                                                     \
        _Pragma("unroll")                                                     \
        for (int n = 0; n < 4; ++n) {                                         \
            sc[0][n] = MFMA16(kfr[1][n], aq[0][1], sc[0][n]);                 \
            sc[1][n] = MFMA16(kfr[1][n], aq[1][1], sc[1][n]);                 \
        }                                                                     \
        __builtin_amdgcn_s_setprio(0);                                        \
        /* raw exp2 + packed bf16 cvt: p = 2^sc, packed pairs RNE */          \
        bf16x8 ap[2][2];                                                      \
        _Pragma("unroll")                                                     \
        for (int f = 0; f < 2; ++f) {                                         \
            float e0[4], e1[4], e2[4], e3[4];                                 \
            _Pragma("unroll")                                                 \
            for (int r = 0; r < 4; ++r) {                                     \
                asm("v_exp_f32 %0, %1" : "=v"(e0[r]) : "v"(sc[f][0][r]));     \
                asm("v_exp_f32 %0, %1" : "=v"(e1[r]) : "v"(sc[f][1][r]));     \
                asm("v_exp_f32 %0, %1" : "=v"(e2[r]) : "v"(sc[f][2][r]));     \
                asm("v_exp_f32 %0, %1" : "=v"(e3[r]) : "v"(sc[f][3][r]));     \
            }                                                                 \
            unsigned q0, q1, q2, q3, q4, q5, q6, q7;                          \
            asm("v_cvt_pk_bf16_f32 %0, %1, %2" : "=v"(q0) : "v"(e0[0]), "v"(e0[1])); \
            asm("v_cvt_pk_bf16_f32 %0, %1, %2" : "=v"(q1) : "v"(e0[2]), "v"(e0[3])); \
            asm("v_cvt_pk_bf16_f32 %0, %1, %2" : "=v"(q2) : "v"(e2[0]), "v"(e2[1])); \
            asm("v_cvt_pk_bf16_f32 %0, %1, %2" : "=v"(q3) : "v"(e2[2]), "v"(e2[3])); \
            asm("v_cvt_pk_bf16_f32 %0, %1, %2" : "=v"(q4) : "v"(e1[0]), "v"(e1[1])); \
            asm("v_cvt_pk_bf16_f32 %0, %1, %2" : "=v"(q5) : "v"(e1[2]), "v"(e1[3])); \
            asm("v_cvt_pk_bf16_f32 %0, %1, %2" : "=v"(q6) : "v"(e3[0]), "v"(e3[1])); \
            asm("v_cvt_pk_bf16_f32 %0, %1, %2" : "=v"(q7) : "v"(e3[2]), "v"(e3[3])); \
            i32x4 w0 = {(int)q0, (int)q1, (int)q2, (int)q3};                  \
            i32x4 w1 = {(int)q4, (int)q5, (int)q6, (int)q7};                  \
            ap[f][0] = __builtin_bit_cast(bf16x8, w0);                        \
            ap[f][1] = __builtin_bit_cast(bf16x8, w1);                        \
        }                                                                     \
        __builtin_amdgcn_s_setprio(1);                                        \
        lacc[0] = MFMA16(ap[0][0], ones, lacc[0]);                            \
        lacc[0] = MFMA16(ap[0][1], ones, lacc[0]);                            \
        lacc[1] = MFMA16(ap[1][0], ones, lacc[1]);                            \
        lacc[1] = MFMA16(ap[1][1], ones, lacc[1]);                            \
        _Pragma("unroll")                                                     \
        for (int kk = 0; kk < 2; ++kk)                                        \
            _Pragma("unroll")                                                 \
            for (int n = 0; n < 4; ++n) {                                     \
                ao[0][n] = MFMA16(ap[0][kk], vfr[kk][n], ao[0][n]);           \
                ao[1][n] = MFMA16(ap[1][kk], vfr[kk][n], ao[1][n]);           \
            }                                                                 \
        __builtin_amdgcn_s_setprio(0);                                        \
    } while (0)

    STAGE(0, 0);
    for (int t = 0; t < 16; t += 2) {
        TILE(t, 0);
        TILE(t + 1, 1);
    }
#undef TILE
#undef STAGE

    // ---- merge: team1 partials -> LDS; team0 adds ----
    // __syncthreads (drain lgkm/vm + barrier) on BOTH sides: raw s_barrier
    // does not drain ds_writes -> r11's replay-divergence race.
    float* mO = (float*)(smem + 16384);   // [128][64] f32 over team1 region
    float* mL = (float*)smem;             // [128] f32 over team0 K buf0
    __syncthreads();                      // all loop LDS reads complete
    if (team == 1) {
#pragma unroll
        for (int f = 0; f < 2; ++f) {
#pragma unroll
            for (int j = 0; j < 4; ++j) {
                const int row = wt * 32 + f * 16 + 4 * l4 + j;
#pragma unroll
                for (int n = 0; n < 4; ++n)
                    mO[row * 64 + 16 * n + l15] = ao[f][n][j];
                if (l15 == 0) mL[row] = lacc[f][j];
            }
        }
    }
    __syncthreads();                      // team1's ds_writes visible
    if (team == 0) {
        // epilogue: add team1 partials, normalize, scrambled store
        //   row r = h*256 + b*128 + (s>>4), feature f = (s&15)*64 + d
#pragma unroll
        for (int f = 0; f < 2; ++f) {
#pragma unroll
            for (int j = 0; j < 4; ++j) {
                const int row = wt * 32 + f * 16 + 4 * l4 + j;
                const float inv = 1.0f / (lacc[f][j] + mL[row]);
                const int s = qb0 + row;
                const size_t base = ((size_t)(h * 256 + b * 128 + (s >> 4))) * 1024
                                  + (s & 15) * 64;
#pragma unroll
                for (int n = 0; n < 4; ++n)
                    ob[base + 16 * n + l15] =
                        (bf16)((ao[f][n][j] + mO[row * 64 + 16 * n + l15]) * inv);
            }
        }
    }
}

// ----------------------------------------------------------- out GEMM ----
__global__ __launch_bounds__(256) void k_gemm_out(const bf16* __restrict__ O,
                                                  const bf16* __restrict__ Wt,
                                                  const float* __restrict__ bo,
                                                  float* __restrict__ out) {
    __shared__ __align__(16) bf16 As[3 * 4096];
    __shared__ __align__(16) bf16 Bs[3 * 4096];
    f32x4 acc[4][4] = {};
    const int nwg = gridDim.x * gridDim.y;
    const int wg  = blockIdx.y * gridDim.x + blockIdx.x;
    const int sw  = (wg & 7) * (nwg >> 3) + (wg >> 3);
    const int m0 = (sw / gridDim.x) * 128, n0 = (sw % gridDim.x) * 128;
    gemm_loop(O, Wt, m0, n0, As, Bs, acc);

    const int tid = threadIdx.x;
    const int w = tid >> 6, lane = tid & 63;
    const int wr = (w >> 1) * 64, wc = (w & 1) * 64;
    const int l15 = lane & 15, l4 = lane >> 4;
#pragma unroll
    for (int m = 0; m < 4; ++m) {
#pragma unroll
        for (int j = 0; j < 4; ++j) {
            const int tok = m0 + wr + 16 * m + 4 * l4 + j;
#pragma unroll
            for (int n = 0; n < 4; ++n) {
                const int feat = n0 + wc + 16 * n + l15;
                out[(size_t)tok * 1024 + feat] = acc[m][n][j] + bo[feat];
            }
        }
    }
}

// -------------------------------------------------------------- launch ----
extern "C" void kernel_launch(void* const* d_in, const int* in_sizes, int n_in,
                              void* d_out, int out_size, void* d_ws, size_t ws_size,
                              hipStream_t stream) {
    (void)in_sizes; (void)n_in; (void)out_size; (void)ws_size;
    const float* x  = (const float*)d_in[0];
    const float* Wq = (const float*)d_in[1];
    const float* bq = (const float*)d_in[2];
    const float* Wk = (const float*)d_in[3];
    const float* bk = (const float*)d_in[4];
    const float* Wv = (const float*)d_in[5];
    const float* bv = (const float*)d_in[6];
    const float* Wo = (const float*)d_in[7];
    const float* bo = (const float*)d_in[8];
    float* out = (float*)d_out;

    char* p = (char*)d_ws;
    bf16* xb    = (bf16*)p;  p += (size_t)4096 * 1024 * 2;   // reused as obuf
    bf16* wqkvt = (bf16*)p;  p += (size_t)3072 * 1024 * 2;
    bf16* wot   = (bf16*)p;  p += (size_t)1024 * 1024 * 2;
    bf16* qbuf  = (bf16*)p;  p += (size_t)32 * 2048 * 64 * 2;
    bf16* kbuf  = (bf16*)p;  p += (size_t)32 * 2048 * 64 * 2;
    bf16* vtb   = (bf16*)p;  p += (size_t)32 * 64 * 2048 * 2;
    float* ct   = (float*)p; p += (size_t)2048 * 32 * 4;
    float* st   = (float*)p; p += (size_t)2048 * 32 * 4;
    bf16* obuf  = xb;  // x no longer needed after QKV GEMM

    k_prep<<<dim3(8448), dim3(256), 0, stream>>>(x, Wq, Wk, Wv, Wo,
                                                 xb, wqkvt, wot, ct, st);
    k_gemm_qkv<<<dim3(12, 32), dim3(256), 0, stream>>>(xb, wqkvt, bq, bk, bv,
                                                       ct, st, qbuf, kbuf, vtb);
    k_attn<<<dim3(512), dim3(512), 0, stream>>>(qbuf, kbuf, vtb, obuf);
    k_gemm_out<<<dim3(8, 32), dim3(256), 0, stream>>>(obuf, wot, bo, out);
}

// Round 17
// 118.154 us; speedup vs baseline: 1.2814x; 1.2814x over previous
//
#include <hip/hip_runtime.h>
#include <hip/hip_bf16.h>
#include <stdint.h>

typedef __bf16 bf16;
typedef __bf16 bf16x8 __attribute__((ext_vector_type(8)));
typedef __bf16 bf16x4 __attribute__((ext_vector_type(4)));
typedef float  f32x4  __attribute__((ext_vector_type(4)));
typedef int    i32x4  __attribute__((ext_vector_type(4)));

#define MFMA16(a, b, c) __builtin_amdgcn_mfma_f32_16x16x32_bf16((a), (b), (c), 0, 0, 0)

#define GLOAD16(gp, lp) __builtin_amdgcn_global_load_lds(                     \
    (__attribute__((address_space(1))) void*)(gp),                            \
    (__attribute__((address_space(3))) void*)(lp), 16, 0, 0)

// Attn K/V LDS tiles are [rows][64] bf16; GEMM tiles [rows][32] bf16, both
// with granule XOR swizzle (staging pre-swizzles the GLOBAL source column;
// LDS dest stays linear for global_load_lds).
//
// V's key axis is sigma-permuted in global memory:
//   key s = 16n+4g+r  ->  sigma(s) = 32*(n&1) + 8*g + 4*(n>>1) + r
// so P stays register-resident in attn (see k_attn header).
//
// r17: QKV reverted to r13's 2-buffer 128x128 loop (r16's 128x256/acc[8][4]
// hit 152 VGPR -> 8% occupancy -> 82 us). Out-GEMM split to 128x64 tiles,
// grid 512 = 2 WG/CU (was 1 WG/CU with zero cross-WG latency hiding).

// ---------------------------------------------------------------- prep ----
__global__ __launch_bounds__(256) void k_prep(
    const float* __restrict__ x,
    const float* __restrict__ Wq, const float* __restrict__ Wk,
    const float* __restrict__ Wv, const float* __restrict__ Wo,
    bf16* __restrict__ xb, bf16* __restrict__ wqkvt, bf16* __restrict__ wot,
    float* __restrict__ ct, float* __restrict__ st) {
    __shared__ float t[32][33];
    const int bid = blockIdx.x, tid = threadIdx.x;
    if (bid < 4096) {
        const int i = bid * 256 + tid;
        float4 v = ((const float4*)x)[i];
        bf16x4 o;
        o[0] = (bf16)v.x; o[1] = (bf16)v.y; o[2] = (bf16)v.z; o[3] = (bf16)v.w;
        ((bf16x4*)xb)[i] = o;
    } else if (bid < 4352) {
        const int i = (bid - 4096) * 256 + tid;  // 65536
        const int s = i >> 5, j = i & 31;
        const float inv = expf(-(float)j * (9.210340371976184f / 32.0f)); // 10000^(-j/32)
        const float a = (float)s * inv;
        ct[i] = cosf(a);
        st[i] = sinf(a);
    } else {
        const int wb = bid - 4352;
        const int z = wb >> 10, tb = wb & 1023;
        const float* src = (z == 0) ? Wq : (z == 1) ? Wk : (z == 2) ? Wv : Wo;
        bf16* dst = (z < 3) ? wqkvt + (size_t)z * 1024 * 1024 : wot;
        const int bx = (tb & 31) * 32, by = (tb >> 5) * 32;
        const int tx = tid & 31, ty = tid >> 5;
#pragma unroll
        for (int i = 0; i < 32; i += 8)
            t[ty + i][tx] = src[(size_t)(by + ty + i) * 1024 + bx + tx];
        __syncthreads();
#pragma unroll
        for (int i = 0; i < 32; i += 8)
            dst[(size_t)(bx + ty + i) * 1024 + by + tx] = (bf16)t[tx][ty + i];
    }
}

// --------------------------------------- QKV mainloop (128x128, 2-buffer) ----
__device__ __forceinline__ void gemm_loop(const bf16* __restrict__ A,
                                          const bf16* __restrict__ Bt,
                                          int m0, int n0,
                                          bf16* As, bf16* Bs,
                                          f32x4 (&acc)[4][4]) {
    const int tid  = threadIdx.x;
    const int w    = tid >> 6, lane = tid & 63;
    const int wr   = (w >> 1) * 64, wc = (w & 1) * 64;
    const int l15  = lane & 15, l4 = lane >> 4;
    const int srow = w * 16 + (lane >> 2);
    const int skol = 8 * ((lane & 3) ^ ((lane >> 3) & 3));
    const int rdb  = l15 * 32 + 8 * (l4 ^ ((l15 >> 1) & 3));
    const bf16* Ap = A  + (size_t)(m0 + srow) * 1024 + skol;
    const bf16* Bp = Bt + (size_t)(n0 + srow) * 1024 + skol;

#define GSTAGE(B, kt) do {                                                   \
        GLOAD16(Ap + (kt),         As + (B) * 4096 + w * 512);               \
        GLOAD16(Ap + 65536 + (kt), As + (B) * 4096 + 2048 + w * 512);        \
        GLOAD16(Bp + (kt),         Bs + (B) * 4096 + w * 512);               \
        GLOAD16(Bp + 65536 + (kt), Bs + (B) * 4096 + 2048 + w * 512);        \
    } while (0)

#define GTILE(t, B) do {                                                     \
        asm volatile("s_waitcnt vmcnt(0)" ::: "memory");                     \
        __builtin_amdgcn_s_barrier();                                        \
        if ((t) < 31) GSTAGE((B) ^ 1, ((t) + 1) * 32);                       \
        bf16x8 af[4], bfv[4];                                                \
        _Pragma("unroll")                                                    \
        for (int m = 0; m < 4; ++m)                                          \
            af[m] = *(const bf16x8*)(As + (B) * 4096 + (wr + 16 * m) * 32 + rdb); \
        _Pragma("unroll")                                                    \
        for (int n = 0; n < 4; ++n)                                          \
            bfv[n] = *(const bf16x8*)(Bs + (B) * 4096 + (wc + 16 * n) * 32 + rdb); \
        __builtin_amdgcn_s_setprio(1);                                       \
        _Pragma("unroll")                                                    \
        for (int m = 0; m < 4; ++m)                                          \
            _Pragma("unroll")                                                \
            for (int n = 0; n < 4; ++n)                                      \
                acc[m][n] = MFMA16(af[m], bfv[n], acc[m][n]);                \
        __builtin_amdgcn_s_setprio(0);                                       \
    } while (0)

    GSTAGE(0, 0);
    for (int t = 0; t < 32; t += 2) {
        GTILE(t, 0);
        GTILE(t + 1, 1);
    }
#undef GTILE
#undef GSTAGE
}

// ------------------------------------------------------------ GEMM QKV ----
__global__ __launch_bounds__(256) void k_gemm_qkv(
    const bf16* __restrict__ X, const bf16* __restrict__ Wt,
    const float* __restrict__ bq, const float* __restrict__ bk,
    const float* __restrict__ bv,
    const float* __restrict__ ct, const float* __restrict__ st,
    bf16* __restrict__ qbuf, bf16* __restrict__ kbuf, bf16* __restrict__ vtb) {
    __shared__ __align__(16) bf16 As[2 * 4096];
    __shared__ __align__(16) bf16 Bs[2 * 4096];
    f32x4 acc[4][4] = {};
    // bijective XCD swizzle: each XCD gets nwg/8 consecutive flat ids
    const int nwg = gridDim.x * gridDim.y;
    const int wg  = blockIdx.y * gridDim.x + blockIdx.x;
    const int sw  = (wg & 7) * (nwg >> 3) + (wg >> 3);
    const int m0 = (sw / gridDim.x) * 128, n0 = (sw % gridDim.x) * 128;
    gemm_loop(X, Wt, m0, n0, As, Bs, acc);

    const int tid = threadIdx.x;
    const int w = tid >> 6, lane = tid & 63;
    const int wr = (w >> 1) * 64, wc = (w & 1) * 64;
    const int l15 = lane & 15, l4 = lane >> 4;

    const int featbase = n0 + wc;          // 64-aligned -> one head, one kind
    const int kind = featbase >> 10;       // 0=Q 1=K 2=V
    const int col0 = featbase & 1023;
    const int h = col0 >> 6;
    const float* bias = (kind == 0) ? bq : (kind == 1) ? bk : bv;
    // Q folds 1/sqrt(64) AND log2(e): attn then uses p = exp2(s) directly.
    const float oscale = (kind == 0) ? 0.18033688011112042f : 1.0f;

#pragma unroll
    for (int m = 0; m < 4; ++m) {
#pragma unroll
        for (int j = 0; j < 4; ++j) {
            const int tok = m0 + wr + 16 * m + 4 * l4 + j;
            const int b = tok >> 11, s = tok & 2047;
            float vals[4];
#pragma unroll
            for (int n = 0; n < 4; ++n)
                vals[n] = acc[m][n][j] + bias[col0 + 16 * n + l15];
            if (kind < 2) {
                bf16* dst = (kind == 0) ? qbuf : kbuf;
                const size_t base = ((size_t)((b * 16 + h) * 2048 + s)) * 64;
#pragma unroll
                for (int n = 0; n < 4; ++n) {
                    const int dd = 16 * n + l15;          // 0..63
                    const int jr = dd & 31;
                    const float c = ct[s * 32 + jr], sn = st[s * 32 + jr];
                    const float other = vals[n ^ 2];       // d +/- 32 partner
                    const float rot = (dd < 32) ? -other : other;
                    dst[base + dd] = (bf16)((vals[n] * c + rot * sn) * oscale);
                }
            } else {
                // sigma-permute key position: s=16n+4g+r -> 32*(n&1)+8*g+4*(n>>1)+r
                const int sp = (s & ~63) | ((s & 0x1C) << 1) | ((s & 0x20) >> 3) | (s & 3);
#pragma unroll
                for (int n = 0; n < 4; ++n) {
                    const int dd = 16 * n + l15;
                    vtb[((size_t)((b * 16 + h) * 64 + dd)) * 2048 + sp] = (bf16)vals[n];
                }
            }
        }
    }
}

// ---------------------------------------------------------- attention ----
// 8 waves/WG, split-K: team = w>>2 handles keys [team*1024, +1024); wt = w&3.
// Each team: KBLK=64, 2-buffer static-indexed K/V, one vmcnt(0)+barrier per
// tile. Softmax pack: raw v_exp_f32 + v_cvt_pk_bf16_f32.
__global__ __launch_bounds__(512) void k_attn(const bf16* __restrict__ qbuf,
                                              const bf16* __restrict__ kbuf,
                                              const bf16* __restrict__ vtb,
                                              bf16* __restrict__ ob) {
    // [team][K/V][buf][4096] bf16 = 64 KB; team1 region doubles as merge buf
    __shared__ __align__(16) bf16 smem[2 * 2 * 2 * 4096];

    const int tid = threadIdx.x, w = tid >> 6, lane = tid & 63;
    const int team = w >> 2, wt = w & 3;
    const int l15 = lane & 15, l4 = lane >> 4;

    // XCD swizzle: 512 blocks round-robin over 8 XCDs; each XCD owns 4 heads.
    const int sid = blockIdx.x;
    const int bh  = (sid & 7) * 4 + ((sid >> 3) >> 4);
    const int qb0 = ((sid >> 3) & 15) * 128;
    const int b = bh >> 4, h = bh & 15;

    // Q fragments (2 per wave, same rows for both teams); force-complete.
    const bf16* qp = qbuf + ((size_t)bh * 2048 + qb0 + wt * 32 + l15) * 64 + 8 * l4;
    i32x4 qr00 = *(const i32x4*)qp;
    i32x4 qr01 = *(const i32x4*)(qp + 32);
    i32x4 qr10 = *(const i32x4*)(qp + 16 * 64);
    i32x4 qr11 = *(const i32x4*)(qp + 16 * 64 + 32);
    asm volatile("" :: "v"(qr00), "v"(qr01), "v"(qr10), "v"(qr11));
    asm volatile("s_waitcnt vmcnt(0)" ::: "memory");
    bf16x8 aq[2][2];
    aq[0][0] = __builtin_bit_cast(bf16x8, qr00);
    aq[0][1] = __builtin_bit_cast(bf16x8, qr01);
    aq[1][0] = __builtin_bit_cast(bf16x8, qr10);
    aq[1][1] = __builtin_bit_cast(bf16x8, qr11);

    bf16x8 ones;
#pragma unroll
    for (int i = 0; i < 8; ++i) ones[i] = (bf16)1.0f;

    f32x4 ao[2][4] = {};
    f32x4 lacc[2] = {};
    const f32x4 zf = {0.f, 0.f, 0.f, 0.f};

    const int r8   = lane >> 3;
    const int skol = 8 * ((lane & 7) ^ r8);           // pre-swizzled source col
    const int rdb  = l15 * 64 + 32 * ((l15 >> 2) & 1) + 8 * (l4 ^ (l15 & 3));
    // global K/V base for this team's key half
    const bf16* kp = kbuf + (size_t)bh * 131072 + (size_t)team * 65536
                   + (size_t)(wt * 8 + r8) * 64 + skol;
    const bf16* vp = vtb  + (size_t)bh * 131072 + (size_t)(wt * 8 + r8) * 2048
                   + team * 1024 + skol;
    // per-team LDS bases
    bf16* sK = smem + team * 16384;            // + B*4096
    bf16* sV = smem + team * 16384 + 8192;     // + B*4096
    const bf16* pK0 = sK + rdb;
    const bf16* pK1 = sK + (rdb ^ 32);
    const bf16* pV0 = sV + rdb;
    const bf16* pV1 = sV + (rdb ^ 32);

#define STAGE(B, t) do {                                                  \
        GLOAD16(kp + (size_t)(t) * 4096,        sK + (B) * 4096 + wt * 512);        \
        GLOAD16(kp + (size_t)(t) * 4096 + 2048, sK + (B) * 4096 + 2048 + wt * 512); \
        GLOAD16(vp + (t) * 64,                  sV + (B) * 4096 + wt * 512);        \
        GLOAD16(vp + 65536 + (t) * 64,          sV + (B) * 4096 + 2048 + wt * 512); \
    } while (0)

#define TILE(t, B) do {                                                       \
        asm volatile("s_waitcnt vmcnt(0)" ::: "memory");                      \
        __builtin_amdgcn_s_barrier();                                         \
        if ((t) < 15) STAGE((B) ^ 1, (t) + 1);                                \
        bf16x8 kfr[2][4], vfr[2][4];                                          \
        _Pragma("unroll")                                                     \
        for (int n = 0; n < 4; ++n) {                                         \
            kfr[0][n] = *(const bf16x8*)(pK0 + (B) * 4096 + n * 1024);        \
            kfr[1][n] = *(const bf16x8*)(pK1 + (B) * 4096 + n * 1024);        \
            vfr[0][n] = *(const bf16x8*)(pV0 + (B) * 4096 + n * 1024);        \
            vfr[1][n] = *(const bf16x8*)(pV1 + (B) * 4096 + n * 1024);        \
        }                                                                     \
        f32x4 sc[2][4];                                                       \
        __builtin_amdgcn_s_setprio(1);                                        \
        _Pragma("unroll")                                                     \
        for (int n = 0; n < 4; ++n) {                                         \
            sc[0][n] = MFMA16(kfr[0][n], aq[0][0], zf);                       \
            sc[1][n] = MFMA16(kfr[0][n], aq[1][0], zf);                       \
        }                                                                     \
        _Pragma("unroll")                                                     \
        for (int n = 0; n < 4; ++n) {                                         \
            sc[0][n] = MFMA16(kfr[1][n], aq[0][1], sc[0][n]);                 \
            sc[1][n] = MFMA16(kfr[1][n], aq[1][1], sc[1][n]);                 \
        }                                                                     \
        __builtin_amdgcn_s_setprio(0);                                        \
        /* raw exp2 + packed bf16 cvt: p = 2^sc, packed pairs RNE */          \
        bf16x8 ap[2][2];                                                      \
        _Pragma("unroll")                                                     \
        for (int f = 0; f < 2; ++f) {                                         \
            float e0[4], e1[4], e2[4], e3[4];                                 \
            _Pragma("unroll")                                                 \
            for (int r = 0; r < 4; ++r) {                                     \
                asm("v_exp_f32 %0, %1" : "=v"(e0[r]) : "v"(sc[f][0][r]));     \
                asm("v_exp_f32 %0, %1" : "=v"(e1[r]) : "v"(sc[f][1][r]));     \
                asm("v_exp_f32 %0, %1" : "=v"(e2[r]) : "v"(sc[f][2][r]));     \
                asm("v_exp_f32 %0, %1" : "=v"(e3[r]) : "v"(sc[f][3][r]));     \
            }                                                                 \
            unsigned q0, q1, q2, q3, q4, q5, q6, q7;                          \
            asm("v_cvt_pk_bf16_f32 %0, %1, %2" : "=v"(q0) : "v"(e0[0]), "v"(e0[1])); \
            asm("v_cvt_pk_bf16_f32 %0, %1, %2" : "=v"(q1) : "v"(e0[2]), "v"(e0[3])); \
            asm("v_cvt_pk_bf16_f32 %0, %1, %2" : "=v"(q2) : "v"(e2[0]), "v"(e2[1])); \
            asm("v_cvt_pk_bf16_f32 %0, %1, %2" : "=v"(q3) : "v"(e2[2]), "v"(e2[3])); \
            asm("v_cvt_pk_bf16_f32 %0, %1, %2" : "=v"(q4) : "v"(e1[0]), "v"(e1[1])); \
            asm("v_cvt_pk_bf16_f32 %0, %1, %2" : "=v"(q5) : "v"(e1[2]), "v"(e1[3])); \
            asm("v_cvt_pk_bf16_f32 %0, %1, %2" : "=v"(q6) : "v"(e3[0]), "v"(e3[1])); \
            asm("v_cvt_pk_bf16_f32 %0, %1, %2" : "=v"(q7) : "v"(e3[2]), "v"(e3[3])); \
            i32x4 w0 = {(int)q0, (int)q1, (int)q2, (int)q3};                  \
            i32x4 w1 = {(int)q4, (int)q5, (int)q6, (int)q7};                  \
            ap[f][0] = __builtin_bit_cast(bf16x8, w0);                        \
            ap[f][1] = __builtin_bit_cast(bf16x8, w1);                        \
        }                                                                     \
        __builtin_amdgcn_s_setprio(1);                                        \
        lacc[0] = MFMA16(ap[0][0], ones, lacc[0]);                            \
        lacc[0] = MFMA16(ap[0][1], ones, lacc[0]);                            \
        lacc[1] = MFMA16(ap[1][0], ones, lacc[1]);                            \
        lacc[1] = MFMA16(ap[1][1], ones, lacc[1]);                            \
        _Pragma("unroll")                                                     \
        for (int kk = 0; kk < 2; ++kk)                                        \
            _Pragma("unroll")                                                 \
            for (int n = 0; n < 4; ++n) {                                     \
                ao[0][n] = MFMA16(ap[0][kk], vfr[kk][n], ao[0][n]);           \
                ao[1][n] = MFMA16(ap[1][kk], vfr[kk][n], ao[1][n]);           \
            }                                                                 \
        __builtin_amdgcn_s_setprio(0);                                        \
    } while (0)

    STAGE(0, 0);
    for (int t = 0; t < 16; t += 2) {
        TILE(t, 0);
        TILE(t + 1, 1);
    }
#undef TILE
#undef STAGE

    // ---- merge: team1 partials -> LDS; team0 adds ----
    // __syncthreads (drain lgkm/vm + barrier) on BOTH sides: raw s_barrier
    // does not drain ds_writes -> r11's replay-divergence race.
    float* mO = (float*)(smem + 16384);   // [128][64] f32 over team1 region
    float* mL = (float*)smem;             // [128] f32 over team0 K buf0
    __syncthreads();                      // all loop LDS reads complete
    if (team == 1) {
#pragma unroll
        for (int f = 0; f < 2; ++f) {
#pragma unroll
            for (int j = 0; j < 4; ++j) {
                const int row = wt * 32 + f * 16 + 4 * l4 + j;
#pragma unroll
                for (int n = 0; n < 4; ++n)
                    mO[row * 64 + 16 * n + l15] = ao[f][n][j];
                if (l15 == 0) mL[row] = lacc[f][j];
            }
        }
    }
    __syncthreads();                      // team1's ds_writes visible
    if (team == 0) {
        // epilogue: add team1 partials, normalize, scrambled store
        //   row r = h*256 + b*128 + (s>>4), feature f = (s&15)*64 + d
#pragma unroll
        for (int f = 0; f < 2; ++f) {
#pragma unroll
            for (int j = 0; j < 4; ++j) {
                const int row = wt * 32 + f * 16 + 4 * l4 + j;
                const float inv = 1.0f / (lacc[f][j] + mL[row]);
                const int s = qb0 + row;
                const size_t base = ((size_t)(h * 256 + b * 128 + (s >> 4))) * 1024
                                  + (s & 15) * 64;
#pragma unroll
                for (int n = 0; n < 4; ++n)
                    ob[base + 16 * n + l15] =
                        (bf16)((ao[f][n][j] + mO[row * 64 + 16 * n + l15]) * inv);
            }
        }
    }
}

// ----------------------------------------------------------- out GEMM ----
// 128(M)x64(N) tile, grid 16x32 = 512 WGs (2 WG/CU), 4 waves with wave-tile
// 64x32 (acc[4][2]), BK=32, 3-buffer LDS (A 24 KB + B 12 KB), prefetch
// distance 2, vmcnt(3) (3-load batches: 2x A + 1x B).
__global__ __launch_bounds__(256) void k_gemm_out(const bf16* __restrict__ O,
                                                  const bf16* __restrict__ Wt,
                                                  const float* __restrict__ bo,
                                                  float* __restrict__ out) {
    __shared__ __align__(16) bf16 As[3 * 4096];   // [buf][128r][32]
    __shared__ __align__(16) bf16 Bs[3 * 2048];   // [buf][64r][32]
    f32x4 acc[4][2] = {};

    const int nwg = gridDim.x * gridDim.y;        // 512, %8 == 0
    const int wg  = blockIdx.y * gridDim.x + blockIdx.x;
    const int sw  = (wg & 7) * (nwg >> 3) + (wg >> 3);
    const int m0 = (sw / gridDim.x) * 128, n0 = (sw % gridDim.x) * 64;

    const int tid  = threadIdx.x;
    const int w    = tid >> 6, lane = tid & 63;
    const int wr   = (w >> 1) * 64, wc = (w & 1) * 32;
    const int l15  = lane & 15, l4 = lane >> 4;
    const int srow = w * 16 + (lane >> 2);
    const int skol = 8 * ((lane & 3) ^ ((lane >> 3) & 3));
    const int rdb  = l15 * 32 + 8 * (l4 ^ ((l15 >> 1) & 3));
    const bf16* Ap = O  + (size_t)(m0 + srow) * 1024 + skol;
    const bf16* Bp = Wt + (size_t)(n0 + srow) * 1024 + skol;

#define OSTAGE(B, kt) do {                                                   \
        GLOAD16(Ap + (kt),         As + (B) * 4096 + w * 512);               \
        GLOAD16(Ap + 65536 + (kt), As + (B) * 4096 + 2048 + w * 512);        \
        GLOAD16(Bp + (kt),         Bs + (B) * 2048 + w * 512);               \
    } while (0)

#define OCOMP(B) do {                                                        \
        bf16x8 af[4], bfv[2];                                                \
        _Pragma("unroll")                                                    \
        for (int m = 0; m < 4; ++m)                                          \
            af[m] = *(const bf16x8*)(As + (B) * 4096 + (wr + 16 * m) * 32 + rdb); \
        _Pragma("unroll")                                                    \
        for (int n = 0; n < 2; ++n)                                          \
            bfv[n] = *(const bf16x8*)(Bs + (B) * 2048 + (wc + 16 * n) * 32 + rdb); \
        __builtin_amdgcn_s_setprio(1);                                       \
        _Pragma("unroll")                                                    \
        for (int m = 0; m < 4; ++m)                                          \
            _Pragma("unroll")                                                \
            for (int n = 0; n < 2; ++n)                                      \
                acc[m][n] = MFMA16(af[m], bfv[n], acc[m][n]);                \
        __builtin_amdgcn_s_setprio(0);                                       \
    } while (0)

    OSTAGE(0, 0);
    OSTAGE(1, 32);
    for (int i = 0; i < 30; i += 3) {
        asm volatile("s_waitcnt vmcnt(3)" ::: "memory");
        __builtin_amdgcn_s_barrier();
        OSTAGE(2, (i + 2) * 32);
        OCOMP(0);
        asm volatile("s_waitcnt vmcnt(3)" ::: "memory");
        __builtin_amdgcn_s_barrier();
        OSTAGE(0, (i + 3) * 32);
        OCOMP(1);
        asm volatile("s_waitcnt vmcnt(3)" ::: "memory");
        __builtin_amdgcn_s_barrier();
        OSTAGE(1, (i + 4) * 32);
        OCOMP(2);
    }
    asm volatile("s_waitcnt vmcnt(3)" ::: "memory");
    __builtin_amdgcn_s_barrier();
    OCOMP(0);
    asm volatile("s_waitcnt vmcnt(0)" ::: "memory");
    __builtin_amdgcn_s_barrier();
    OCOMP(1);
#undef OCOMP
#undef OSTAGE

#pragma unroll
    for (int m = 0; m < 4; ++m) {
#pragma unroll
        for (int j = 0; j < 4; ++j) {
            const int tok = m0 + wr + 16 * m + 4 * l4 + j;
#pragma unroll
            for (int n = 0; n < 2; ++n) {
                const int feat = n0 + wc + 16 * n + l15;
                out[(size_t)tok * 1024 + feat] = acc[m][n][j] + bo[feat];
            }
        }
    }
}

// -------------------------------------------------------------- launch ----
extern "C" void kernel_launch(void* const* d_in, const int* in_sizes, int n_in,
                              void* d_out, int out_size, void* d_ws, size_t ws_size,
                              hipStream_t stream) {
    (void)in_sizes; (void)n_in; (void)out_size; (void)ws_size;
    const float* x  = (const float*)d_in[0];
    const float* Wq = (const float*)d_in[1];
    const float* bq = (const float*)d_in[2];
    const float* Wk = (const float*)d_in[3];
    const float* bk = (const float*)d_in[4];
    const float* Wv = (const float*)d_in[5];
    const float* bv = (const float*)d_in[6];
    const float* Wo = (const float*)d_in[7];
    const float* bo = (const float*)d_in[8];
    float* out = (float*)d_out;

    char* p = (char*)d_ws;
    bf16* xb    = (bf16*)p;  p += (size_t)4096 * 1024 * 2;   // reused as obuf
    bf16* wqkvt = (bf16*)p;  p += (size_t)3072 * 1024 * 2;
    bf16* wot   = (bf16*)p;  p += (size_t)1024 * 1024 * 2;
    bf16* qbuf  = (bf16*)p;  p += (size_t)32 * 2048 * 64 * 2;
    bf16* kbuf  = (bf16*)p;  p += (size_t)32 * 2048 * 64 * 2;
    bf16* vtb   = (bf16*)p;  p += (size_t)32 * 64 * 2048 * 2;
    float* ct   = (float*)p; p += (size_t)2048 * 32 * 4;
    float* st   = (float*)p; p += (size_t)2048 * 32 * 4;
    bf16* obuf  = xb;  // x no longer needed after QKV GEMM

    k_prep<<<dim3(8448), dim3(256), 0, stream>>>(x, Wq, Wk, Wv, Wo,
                                                 xb, wqkvt, wot, ct, st);
    k_gemm_qkv<<<dim3(24, 32), dim3(256), 0, stream>>>(xb, wqkvt, bq, bk, bv,
                                                       ct, st, qbuf, kbuf, vtb);
    k_attn<<<dim3(512), dim3(512), 0, stream>>>(qbuf, kbuf, vtb, obuf);
    k_gemm_out<<<dim3(16, 32), dim3(256), 0, stream>>>(obuf, wot, bo, out);
}